// Round 6
// baseline (899.921 us; speedup 1.0000x reference)
//
#include <hip/hip_runtime.h>
#include <hip/hip_bf16.h>

#define BB 8
#define TT 2048
#define DD 512
#define SQRTD 22.62741699796952f

typedef float fv4 __attribute__((ext_vector_type(4)));
typedef short bv8 __attribute__((ext_vector_type(8)));
typedef short bv4 __attribute__((ext_vector_type(4)));

__device__ __forceinline__ short f2bf(float f) {
  __hip_bfloat16 h = __float2bfloat16(f);
  return *reinterpret_cast<short*>(&h);
}
__device__ __forceinline__ float bf2f(short s) {
  union { unsigned u; float f; } a; a.u = ((unsigned)(unsigned short)s) << 16;
  return a.f;
}

__device__ __forceinline__ void gld_lds16(const void* g, void* l) {
  __builtin_amdgcn_global_load_lds(
      (const __attribute__((address_space(1))) void*)g,
      (__attribute__((address_space(3))) void*)l, 16, 0, 0);
}

// ---------------- K1: fused projection GEMM: C = X @ W^T (f32 in, bf16 out)
__global__ __launch_bounds__(256, 2) void k_proj(
    const float* __restrict__ Xq, const float* __restrict__ Xk, const float* __restrict__ Xv,
    const float* __restrict__ Wq, const float* __restrict__ Wk, const float* __restrict__ Wv,
    short* __restrict__ Qb, short* __restrict__ Kb, short* __restrict__ Vb)
{
  __shared__ short At[128 * 64];
  __shared__ short Bt[128 * 64];
  const int z = blockIdx.z;
  const float* __restrict__ X = (z == 0) ? Xq : (z == 1) ? Xk : Xv;
  const float* __restrict__ W = (z == 0) ? Wq : (z == 1) ? Wk : Wv;
  short* __restrict__ C = (z == 0) ? Qb : (z == 1) ? Kb : Vb;
  const int m0 = blockIdx.x * 128;
  const int n0 = blockIdx.y * 128;
  const int t = threadIdx.x;
  const int lane = t & 63;
  const int w = t >> 6;
  const int wr = (w >> 1) * 64, wc = (w & 1) * 64;
  fv4 acc[4][4] = {};
  for (int kt = 0; kt < DD; kt += 64) {
    #pragma unroll
    for (int j = 0; j < 8; ++j) {
      int f = j * 256 + t;
      int row = f >> 4, c4 = f & 15;
      int byte = (row * 128 + c4 * 8) ^ ((row & 7) << 4);
      fv4 va = *(const fv4*)(X + (size_t)(m0 + row) * DD + kt + c4 * 4);
      bv4 ha;
      #pragma unroll
      for (int e = 0; e < 4; ++e) ha[e] = f2bf(va[e]);
      *(bv4*)((char*)At + byte) = ha;
      fv4 vb = *(const fv4*)(W + (size_t)(n0 + row) * DD + kt + c4 * 4);
      bv4 hb;
      #pragma unroll
      for (int e = 0; e < 4; ++e) hb[e] = f2bf(vb[e]);
      *(bv4*)((char*)Bt + byte) = hb;
    }
    __syncthreads();
    #pragma unroll
    for (int ks = 0; ks < 2; ++ks) {
      bv8 af[4], bfr[4];
      #pragma unroll
      for (int i = 0; i < 4; ++i) {
        int ra = wr + i * 16 + (lane & 15);
        af[i] = *(bv8*)((char*)At + ((ra * 128 + ks * 64 + ((lane >> 4) * 16)) ^ ((ra & 7) << 4)));
        int rb = wc + i * 16 + (lane & 15);
        bfr[i] = *(bv8*)((char*)Bt + ((rb * 128 + ks * 64 + ((lane >> 4) * 16)) ^ ((rb & 7) << 4)));
      }
      #pragma unroll
      for (int mi = 0; mi < 4; ++mi)
        #pragma unroll
        for (int ni = 0; ni < 4; ++ni)
          acc[mi][ni] = __builtin_amdgcn_mfma_f32_16x16x32_bf16(af[mi], bfr[ni], acc[mi][ni], 0, 0, 0);
    }
    __syncthreads();
  }
  #pragma unroll
  for (int mi = 0; mi < 4; ++mi)
    #pragma unroll
    for (int r = 0; r < 4; ++r) {
      int gm = m0 + wr + mi * 16 + ((lane >> 4) << 2) + r;
      #pragma unroll
      for (int ni = 0; ni < 4; ++ni) {
        int gn = n0 + wc + ni * 16 + (lane & 15);
        C[(size_t)gm * DD + gn] = f2bf(acc[mi][ni][r]);
      }
    }
}

// ---------------- K1b: transpose V (B,T,D) -> Vt (B,D,T), bf16
__global__ __launch_bounds__(256) void k_transpose(
    const short* __restrict__ Vb, short* __restrict__ Vt)
{
  __shared__ short tile[64][72];
  const int b = blockIdx.z;
  const int t0 = blockIdx.x * 64;
  const int d0 = blockIdx.y * 64;
  const int t = threadIdx.x;
  #pragma unroll
  for (int j = 0; j < 2; ++j) {
    int f = j * 256 + t;
    int row = f >> 3, c8 = f & 7;
    bv8 v = *(const bv8*)(Vb + ((size_t)b * TT + t0 + row) * DD + d0 + c8 * 8);
    *(bv8*)&tile[row][c8 * 8] = v;
  }
  __syncthreads();
  #pragma unroll
  for (int j = 0; j < 2; ++j) {
    int f = j * 256 + t;
    int drow = f >> 3, c8 = f & 7;
    bv8 v;
    #pragma unroll
    for (int e = 0; e < 8; ++e) v[e] = tile[c8 * 8 + e][drow];
    *(bv8*)(Vt + ((size_t)b * DD + d0 + drow) * TT + t0 + c8 * 8) = v;
  }
}

// ---------------- K2: fused attention, KV-split (h = key half).
// QBLK=64, 8 waves (rg = q 16-group, kg = key 16-group), 32 strips of 32 keys.
// K double-buffered 2x32KB via global_load_lds (pre-swizzled src, linear dest);
// issue order V -> glds -> mask (sched_barrier pinned); bar2 vmcnt(4) retires
// glds only, mask prefetch stays in flight. Writes unnormalized O + l partials.
__global__ __launch_bounds__(512, 4) void k_attn(
    const short* __restrict__ Qb, const short* __restrict__ Kb,
    const short* __restrict__ Vt, const float* __restrict__ mask,
    float* __restrict__ Opart, float* __restrict__ Lp)
{
  __shared__ short Ks[2][32 * 512];  // 2 x 32KB, rows of 1KB
  __shared__ short Ps[64 * 32];      // 4KB, rows of 64B, XOR-swizzled (bijective)
  __shared__ float ls[4][2][16];
  const int b = blockIdx.x;          // batch on x => XCD-pinned
  const int q0 = blockIdx.y * 64;
  const int h = blockIdx.z;          // key half: strips [h*32, h*32+32)
  const int t = threadIdx.x;
  const int lane = t & 63;
  const int w = t >> 6;              // 0..7
  const int rg = w >> 1, kg = w & 1;
  const int l15 = lane & 15, l4 = lane >> 4;
  const int lo16 = lane * 16;

  const char* __restrict__ KbaseB = (const char*)(Kb + (size_t)b * TT * DD);
  const float* __restrict__ Mbase = mask + ((size_t)b * TT + q0) * TT;

  // hoist Q fragments: 16 rows (rg group), full D=512
  bv8 qf[16];
  #pragma unroll
  for (int kk = 0; kk < 16; ++kk)
    qf[kk] = *(const bv8*)(Qb + ((size_t)b * TT + q0 + rg * 16 + l15) * DD + kk * 32 + l4 * 8);

  fv4 o[4][4] = {};
  float rsum[4] = {0.f, 0.f, 0.f, 0.f};
  float mko[4], mkn[4];

  // prologue: glds K(strip h*32) -> buf0 (wave w owns rows [4w,4w+4))
  {
    const char* Kstrip = KbaseB + (size_t)(h * 32) * 32768;
    #pragma unroll
    for (int i = 0; i < 4; ++i) {
      int row = w * 4 + i;
      gld_lds16(Kstrip + row * 1024 + (lo16 ^ ((row & 7) << 4)), &Ks[0][row * 512]);
    }
  }
  #pragma unroll
  for (int r = 0; r < 4; ++r)
    mko[r] = Mbase[(size_t)(rg * 16 + l4 * 4 + r) * TT + (size_t)(h * 32) * 32 + kg * 16 + l15];
  // glds retired (4 newest = mask loads stay)
  asm volatile("s_waitcnt vmcnt(4) lgkmcnt(0)\n\ts_barrier" ::: "memory");

  #pragma unroll 2
  for (int j = 0; j < 32; ++j) {
    const int nt = h * 32 + j;
    const int ntn = h * 32 + ((j + 1) & 31);
    const int buf = j & 1;

    // ---- V(t) first (oldest in vmcnt FIFO; retired by compiler before PV)
    bv8 vreg[4];
    #pragma unroll
    for (int ni = 0; ni < 4; ++ni)
      vreg[ni] = *(const bv8*)(Vt + ((size_t)b * DD + w * 64 + ni * 16 + l15) * TT + nt * 32 + l4 * 8);
    __builtin_amdgcn_sched_barrier(0);

    // ---- glds K(t+1) -> other buffer
    {
      const char* Kstrip = KbaseB + (size_t)ntn * 32768;
      #pragma unroll
      for (int i = 0; i < 4; ++i) {
        int row = w * 4 + i;
        gld_lds16(Kstrip + row * 1024 + (lo16 ^ ((row & 7) << 4)), &Ks[buf ^ 1][row * 512]);
      }
    }
    __builtin_amdgcn_sched_barrier(0);

    // ---- mask(t+1) (newest; stays in flight across bar2)
    #pragma unroll
    for (int r = 0; r < 4; ++r)
      mkn[r] = Mbase[(size_t)(rg * 16 + l4 * 4 + r) * TT + (size_t)ntn * 32 + kg * 16 + l15];
    __builtin_amdgcn_sched_barrier(0);

    // ---- QK^T: 16x16 tile per wave, K=512, 4 independent chains
    const int krow = kg * 16 + l15;
    const int ksw = (krow & 7) << 4;
    const char* KsR = (const char*)Ks[buf];
    fv4 s0 = {}, s1 = {}, s2 = {}, s3 = {};
    __builtin_amdgcn_s_setprio(1);
    #pragma unroll
    for (int kk = 0; kk < 16; kk += 4) {
      bv8 kf0 = *(const bv8*)(KsR + krow * 1024 + (((kk + 0) * 64 + l4 * 16) ^ ksw));
      bv8 kf1 = *(const bv8*)(KsR + krow * 1024 + (((kk + 1) * 64 + l4 * 16) ^ ksw));
      bv8 kf2 = *(const bv8*)(KsR + krow * 1024 + (((kk + 2) * 64 + l4 * 16) ^ ksw));
      bv8 kf3 = *(const bv8*)(KsR + krow * 1024 + (((kk + 3) * 64 + l4 * 16) ^ ksw));
      s0 = __builtin_amdgcn_mfma_f32_16x16x32_bf16(qf[kk + 0], kf0, s0, 0, 0, 0);
      s1 = __builtin_amdgcn_mfma_f32_16x16x32_bf16(qf[kk + 1], kf1, s1, 0, 0, 0);
      s2 = __builtin_amdgcn_mfma_f32_16x16x32_bf16(qf[kk + 2], kf2, s2, 0, 0, 0);
      s3 = __builtin_amdgcn_mfma_f32_16x16x32_bf16(qf[kk + 3], kf3, s3, 0, 0, 0);
    }
    __builtin_amdgcn_s_setprio(0);
    fv4 sa = (s0 + s1) + (s2 + s3);

    // ---- epilogue: scale + mask + exp -> Ps (swizzled), partial row sums
    #pragma unroll
    for (int r = 0; r < 4; ++r) {
      int row = rg * 16 + l4 * 4 + r;
      float sx = sa[r] * SQRTD + mko[r];
      float pv = __expf(sx);
      short pb = f2bf(pv);
      rsum[r] += bf2f(pb);
      *((short*)((char*)Ps + ((row * 64 + (kg * 16 + l15) * 2) ^ ((row & 7) << 4)))) = pb;
    }
    #pragma unroll
    for (int r = 0; r < 4; ++r) mko[r] = mkn[r];

    // bar1: Ps visible; all waves done reading Ks[buf]. No vmcnt drain.
    asm volatile("s_waitcnt lgkmcnt(0)\n\ts_barrier" ::: "memory");

    // ---- PV: wave w owns d-cols [64w, 64w+64)
    __builtin_amdgcn_s_setprio(1);
    #pragma unroll
    for (int mi = 0; mi < 4; ++mi) {
      int prow = mi * 16 + l15;
      bv8 pa = *(const bv8*)((const char*)Ps + ((prow * 64 + l4 * 16) ^ ((prow & 7) << 4)));
      #pragma unroll
      for (int ni = 0; ni < 4; ++ni)
        o[mi][ni] = __builtin_amdgcn_mfma_f32_16x16x32_bf16(pa, vreg[ni], o[mi][ni], 0, 0, 0);
    }
    __builtin_amdgcn_s_setprio(0);

    // bar2: glds(t+1) retired (vmcnt 8 -> 4), mask(t+1) stays in flight.
    asm volatile("s_waitcnt vmcnt(4) lgkmcnt(0)\n\ts_barrier" ::: "memory");
  }

  // row-sum reduction over 16 key-residues, then across kg
  #pragma unroll
  for (int r = 0; r < 4; ++r) {
    float v = rsum[r];
    v += __shfl_xor(v, 1);
    v += __shfl_xor(v, 2);
    v += __shfl_xor(v, 4);
    v += __shfl_xor(v, 8);
    if (l15 == 0) ls[rg][kg][l4 * 4 + r] = v;
  }
  __syncthreads();
  const size_t hoff = (size_t)h * BB * TT * DD;
  #pragma unroll
  for (int mi = 0; mi < 4; ++mi)
    #pragma unroll
    for (int r = 0; r < 4; ++r) {
      int idx = l4 * 4 + r;
      int grow = q0 + mi * 16 + idx;
      #pragma unroll
      for (int ni = 0; ni < 4; ++ni)
        Opart[hoff + ((size_t)b * TT + grow) * DD + w * 64 + ni * 16 + l15] = o[mi][ni][r];
    }
  if (w == 0 && l15 == 0) {
    #pragma unroll
    for (int mi = 0; mi < 4; ++mi)
      #pragma unroll
      for (int r = 0; r < 4; ++r)
        Lp[(size_t)h * BB * TT + (size_t)b * TT + q0 + mi * 16 + l4 * 4 + r] =
            ls[mi][0][l4 * 4 + r] + ls[mi][1][l4 * 4 + r];
  }
}

// ---------------- K3: combine halves: Out = (O0 + O1) / (l0 + l1)
__global__ __launch_bounds__(256) void k_combine(
    const float* __restrict__ O0, const float* __restrict__ O1,
    const float* __restrict__ L0, const float* __restrict__ L1,
    float* __restrict__ Out)
{
  size_t i = (size_t)blockIdx.x * 256 + threadIdx.x;   // fv4 index
  size_t row = i >> 7;                                  // DD/4 = 128 fv4 per row
  float inv = 1.0f / (L0[row] + L1[row]);
  fv4 a = ((const fv4*)O0)[i];
  fv4 c = ((const fv4*)O1)[i];
  fv4 res;
  #pragma unroll
  for (int e = 0; e < 4; ++e) res[e] = (a[e] + c[e]) * inv;
  ((fv4*)Out)[i] = res;
}

extern "C" void kernel_launch(void* const* d_in, const int* in_sizes, int n_in,
                              void* d_out, int out_size, void* d_ws, size_t ws_size,
                              hipStream_t stream) {
  const float* ft_q = (const float*)d_in[0];
  const float* ft_k = (const float*)d_in[1];
  const float* ft_v = (const float*)d_in[2];
  const float* mask = (const float*)d_in[3];
  const float* Wq   = (const float*)d_in[4];
  const float* Wk   = (const float*)d_in[5];
  const float* Wv   = (const float*)d_in[6];
  float* Out = (float*)d_out;

  const size_t nBTD = (size_t)BB * TT * DD;   // 8,388,608
  short* Qb = (short*)d_ws;
  short* Kb = Qb + nBTD;
  short* Vb = Kb + nBTD;
  short* Vt = Vb + nBTD;
  float* O0 = (float*)(Vt + nBTD);
  float* O1 = O0 + nBTD;
  float* L0 = O1 + nBTD;
  float* L1 = L0 + (size_t)BB * TT;

  k_proj<<<dim3(128, 4, 3), 256, 0, stream>>>(ft_q, ft_k, ft_v, Wq, Wk, Wv, Qb, Kb, Vb);
  k_transpose<<<dim3(TT / 64, DD / 64, BB), 256, 0, stream>>>(Vb, Vt);
  k_attn<<<dim3(BB, TT / 64, 2), 512, 0, stream>>>(Qb, Kb, Vt, mask, O0, L0);
  k_combine<<<(unsigned)(nBTD / 4 / 256), 256, 0, stream>>>(O0, O1, L0, L1, Out);
}

// Round 7
// 257.139 us; speedup vs baseline: 3.4998x; 3.4998x over previous
//
#include <hip/hip_runtime.h>
#include <hip/hip_bf16.h>

#define BB 8
#define TT 2048
#define DD 512
#define SQRTD 22.62741699796952f

typedef float fv4 __attribute__((ext_vector_type(4)));
typedef short bv8 __attribute__((ext_vector_type(8)));
typedef short bv4 __attribute__((ext_vector_type(4)));

__device__ __forceinline__ short f2bf(float f) {
  __hip_bfloat16 h = __float2bfloat16(f);
  return *reinterpret_cast<short*>(&h);
}
__device__ __forceinline__ float bf2f(short s) {
  union { unsigned u; float f; } a; a.u = ((unsigned)(unsigned short)s) << 16;
  return a.f;
}

__device__ __forceinline__ void gld_lds16(const void* g, void* l) {
  __builtin_amdgcn_global_load_lds(
      (const __attribute__((address_space(1))) void*)g,
      (__attribute__((address_space(3))) void*)l, 16, 0, 0);
}

// ---------------- K1: fused projection GEMM: C = X @ W^T (f32 in, bf16 out)
__global__ __launch_bounds__(256, 2) void k_proj(
    const float* __restrict__ Xq, const float* __restrict__ Xk, const float* __restrict__ Xv,
    const float* __restrict__ Wq, const float* __restrict__ Wk, const float* __restrict__ Wv,
    short* __restrict__ Qb, short* __restrict__ Kb, short* __restrict__ Vb)
{
  __shared__ short At[128 * 64];
  __shared__ short Bt[128 * 64];
  const int z = blockIdx.z;
  const float* __restrict__ X = (z == 0) ? Xq : (z == 1) ? Xk : Xv;
  const float* __restrict__ W = (z == 0) ? Wq : (z == 1) ? Wk : Wv;
  short* __restrict__ C = (z == 0) ? Qb : (z == 1) ? Kb : Vb;
  const int m0 = blockIdx.x * 128;
  const int n0 = blockIdx.y * 128;
  const int t = threadIdx.x;
  const int lane = t & 63;
  const int w = t >> 6;
  const int wr = (w >> 1) * 64, wc = (w & 1) * 64;
  fv4 acc[4][4] = {};
  for (int kt = 0; kt < DD; kt += 64) {
    #pragma unroll
    for (int j = 0; j < 8; ++j) {
      int f = j * 256 + t;
      int row = f >> 4, c4 = f & 15;
      int byte = (row * 128 + c4 * 8) ^ ((row & 7) << 4);
      fv4 va = *(const fv4*)(X + (size_t)(m0 + row) * DD + kt + c4 * 4);
      bv4 ha;
      #pragma unroll
      for (int e = 0; e < 4; ++e) ha[e] = f2bf(va[e]);
      *(bv4*)((char*)At + byte) = ha;
      fv4 vb = *(const fv4*)(W + (size_t)(n0 + row) * DD + kt + c4 * 4);
      bv4 hb;
      #pragma unroll
      for (int e = 0; e < 4; ++e) hb[e] = f2bf(vb[e]);
      *(bv4*)((char*)Bt + byte) = hb;
    }
    __syncthreads();
    #pragma unroll
    for (int ks = 0; ks < 2; ++ks) {
      bv8 af[4], bfr[4];
      #pragma unroll
      for (int i = 0; i < 4; ++i) {
        int ra = wr + i * 16 + (lane & 15);
        af[i] = *(bv8*)((char*)At + ((ra * 128 + ks * 64 + ((lane >> 4) * 16)) ^ ((ra & 7) << 4)));
        int rb = wc + i * 16 + (lane & 15);
        bfr[i] = *(bv8*)((char*)Bt + ((rb * 128 + ks * 64 + ((lane >> 4) * 16)) ^ ((rb & 7) << 4)));
      }
      #pragma unroll
      for (int mi = 0; mi < 4; ++mi)
        #pragma unroll
        for (int ni = 0; ni < 4; ++ni)
          acc[mi][ni] = __builtin_amdgcn_mfma_f32_16x16x32_bf16(af[mi], bfr[ni], acc[mi][ni], 0, 0, 0);
    }
    __syncthreads();
  }
  #pragma unroll
  for (int mi = 0; mi < 4; ++mi)
    #pragma unroll
    for (int r = 0; r < 4; ++r) {
      int gm = m0 + wr + mi * 16 + ((lane >> 4) << 2) + r;
      #pragma unroll
      for (int ni = 0; ni < 4; ++ni) {
        int gn = n0 + wc + ni * 16 + (lane & 15);
        C[(size_t)gm * DD + gn] = f2bf(acc[mi][ni][r]);
      }
    }
}

// ---------------- K1b: transpose V (B,T,D) -> Vt (B,D,T), bf16
__global__ __launch_bounds__(256) void k_transpose(
    const short* __restrict__ Vb, short* __restrict__ Vt)
{
  __shared__ short tile[64][72];
  const int b = blockIdx.z;
  const int t0 = blockIdx.x * 64;
  const int d0 = blockIdx.y * 64;
  const int t = threadIdx.x;
  #pragma unroll
  for (int j = 0; j < 2; ++j) {
    int f = j * 256 + t;
    int row = f >> 3, c8 = f & 7;
    bv8 v = *(const bv8*)(Vb + ((size_t)b * TT + t0 + row) * DD + d0 + c8 * 8);
    *(bv8*)&tile[row][c8 * 8] = v;
  }
  __syncthreads();
  #pragma unroll
  for (int j = 0; j < 2; ++j) {
    int f = j * 256 + t;
    int drow = f >> 3, c8 = f & 7;
    bv8 v;
    #pragma unroll
    for (int e = 0; e < 8; ++e) v[e] = tile[c8 * 8 + e][drow];
    *(bv8*)(Vt + ((size_t)b * DD + d0 + drow) * TT + t0 + c8 * 8) = v;
  }
}

// ---------------- K2: fused attention, KV-split (h = key half).
// Round-3 geometry: QBLK=64 q-rows, 8 waves (rg = q 16-group, kg = key 16-group),
// 32 strips of 32 keys per half. K staged via single-buffer global_load_lds
// issued after bar1 (pre-swizzled src, linear dest); bar2 vmcnt(4) retires the
// glds, mask prefetch stays in flight. Writes unnormalized O + l partials.
__global__ __launch_bounds__(512, 2) void k_attn(
    const short* __restrict__ Qb, const short* __restrict__ Kb,
    const short* __restrict__ Vt, const float* __restrict__ mask,
    float* __restrict__ Opart, float* __restrict__ Lp)
{
  __shared__ short Ks[32 * 512];   // 32 KB, rows of 1KB, linear dest
  __shared__ short Ps[64 * 32];    // 4 KB, rows of 64B, XOR-swizzled
  __shared__ float ls[4][2][16];
  const int b = blockIdx.x;        // batch on x => XCD-pinned
  const int q0 = blockIdx.y * 64;
  const int h = blockIdx.z;        // key half: strips [h*32, h*32+32)
  const int t = threadIdx.x;
  const int lane = t & 63;
  const int w = t >> 6;            // 0..7
  const int rg = w >> 1, kg = w & 1;
  const int l15 = lane & 15, l4 = lane >> 4;
  const int lo16 = lane * 16;

  const char* __restrict__ Kbase = (const char*)(Kb + (size_t)b * TT * DD);
  const float* __restrict__ Mbase = mask + ((size_t)b * TT + q0) * TT;

  // hoist Q fragments: 16 rows (rg group), full D=512
  bv8 qf[16];
  #pragma unroll
  for (int kk = 0; kk < 16; ++kk)
    qf[kk] = *(const bv8*)(Qb + ((size_t)b * TT + q0 + rg * 16 + l15) * DD + kk * 32 + l4 * 8);

  fv4 o[4][4] = {};
  float rsum[4] = {0.f, 0.f, 0.f, 0.f};
  float mko[4], mkn[4];

  // prologue: glds K(first strip of this half); wave w owns rows [4w, 4w+4)
  {
    const char* Kstrip = Kbase + (size_t)(h * 32) * 32768;
    #pragma unroll
    for (int i = 0; i < 4; ++i) {
      int row = w * 4 + i;
      gld_lds16(Kstrip + row * 1024 + (lo16 ^ ((row & 7) << 4)), Ks + row * 512);
    }
  }
  __builtin_amdgcn_sched_barrier(0);
  // prologue: mask(first strip)
  #pragma unroll
  for (int r = 0; r < 4; ++r)
    mko[r] = Mbase[(size_t)(rg * 16 + l4 * 4 + r) * TT + h * 1024 + kg * 16 + l15];
  // retire glds (4 newest = mask loads stay in flight)
  asm volatile("s_waitcnt vmcnt(4) lgkmcnt(0)\n\ts_barrier" ::: "memory");

  for (int j = 0; j < 32; ++j) {
    const int nt = h * 32 + j;
    const int ntn = h * 32 + ((j + 1) & 31);

    // ---- V(t) (oldest in vmcnt FIFO; compiler waits before PV consumes it)
    bv8 vreg[4];
    #pragma unroll
    for (int ni = 0; ni < 4; ++ni)
      vreg[ni] = *(const bv8*)(Vt + ((size_t)b * DD + w * 64 + ni * 16 + l15) * TT + nt * 32 + l4 * 8);
    __builtin_amdgcn_sched_barrier(0);

    // ---- QK^T: 16x16 tile per wave, K=512, 4 independent chains
    const int krow = kg * 16 + l15;
    const int ksw = (krow & 7) << 4;
    fv4 s0 = {}, s1 = {}, s2 = {}, s3 = {};
    __builtin_amdgcn_s_setprio(1);
    #pragma unroll
    for (int kk = 0; kk < 16; kk += 4) {
      bv8 kf0 = *(const bv8*)((const char*)Ks + krow * 1024 + (((kk + 0) * 64 + l4 * 16) ^ ksw));
      bv8 kf1 = *(const bv8*)((const char*)Ks + krow * 1024 + (((kk + 1) * 64 + l4 * 16) ^ ksw));
      bv8 kf2 = *(const bv8*)((const char*)Ks + krow * 1024 + (((kk + 2) * 64 + l4 * 16) ^ ksw));
      bv8 kf3 = *(const bv8*)((const char*)Ks + krow * 1024 + (((kk + 3) * 64 + l4 * 16) ^ ksw));
      s0 = __builtin_amdgcn_mfma_f32_16x16x32_bf16(qf[kk + 0], kf0, s0, 0, 0, 0);
      s1 = __builtin_amdgcn_mfma_f32_16x16x32_bf16(qf[kk + 1], kf1, s1, 0, 0, 0);
      s2 = __builtin_amdgcn_mfma_f32_16x16x32_bf16(qf[kk + 2], kf2, s2, 0, 0, 0);
      s3 = __builtin_amdgcn_mfma_f32_16x16x32_bf16(qf[kk + 3], kf3, s3, 0, 0, 0);
    }
    __builtin_amdgcn_s_setprio(0);
    fv4 sa = (s0 + s1) + (s2 + s3);

    // ---- epilogue: scale + mask + exp -> Ps (swizzled), partial row sums
    #pragma unroll
    for (int r = 0; r < 4; ++r) {
      int row = rg * 16 + l4 * 4 + r;
      float sx = sa[r] * SQRTD + mko[r];
      float pv = __expf(sx);
      short pb = f2bf(pv);
      rsum[r] += bf2f(pb);
      *((short*)((char*)Ps + ((row * 64 + (kg * 16 + l15) * 2) ^ ((row & 7) << 4)))) = pb;
    }

    // bar1: Ps visible; all waves done reading Ks(t). No vmcnt drain.
    asm volatile("s_waitcnt lgkmcnt(0)\n\ts_barrier" ::: "memory");

    // ---- glds K(t+1) into Ks (all waves past bar1 => safe to overwrite)
    {
      const char* Kstrip = Kbase + (size_t)ntn * 32768;
      #pragma unroll
      for (int i = 0; i < 4; ++i) {
        int row = w * 4 + i;
        gld_lds16(Kstrip + row * 1024 + (lo16 ^ ((row & 7) << 4)), Ks + row * 512);
      }
    }
    __builtin_amdgcn_sched_barrier(0);
    // ---- mask(t+1) (newest; rides across bar2)
    #pragma unroll
    for (int r = 0; r < 4; ++r)
      mkn[r] = Mbase[(size_t)(rg * 16 + l4 * 4 + r) * TT + (size_t)ntn * 32 + kg * 16 + l15];
    __builtin_amdgcn_sched_barrier(0);

    // ---- PV: wave w owns d-cols [64w, 64w+64)
    __builtin_amdgcn_s_setprio(1);
    #pragma unroll
    for (int mi = 0; mi < 4; ++mi) {
      int prow = mi * 16 + l15;
      bv8 pa = *(const bv8*)((const char*)Ps + ((prow * 64 + l4 * 16) ^ ((prow & 7) << 4)));
      #pragma unroll
      for (int ni = 0; ni < 4; ++ni)
        o[mi][ni] = __builtin_amdgcn_mfma_f32_16x16x32_bf16(pa, vreg[ni], o[mi][ni], 0, 0, 0);
    }
    __builtin_amdgcn_s_setprio(0);
    #pragma unroll
    for (int r = 0; r < 4; ++r) mko[r] = mkn[r];

    // bar2: outstanding = [glds x4][mask x4]; vmcnt(4) retires glds only.
    asm volatile("s_waitcnt vmcnt(4) lgkmcnt(0)\n\ts_barrier" ::: "memory");
  }

  // row-sum reduction over 16 key-residues, then across kg
  #pragma unroll
  for (int r = 0; r < 4; ++r) {
    float v = rsum[r];
    v += __shfl_xor(v, 1);
    v += __shfl_xor(v, 2);
    v += __shfl_xor(v, 4);
    v += __shfl_xor(v, 8);
    if (l15 == 0) ls[rg][kg][l4 * 4 + r] = v;
  }
  __syncthreads();
  const size_t hoff = (size_t)h * BB * TT * DD;
  #pragma unroll
  for (int mi = 0; mi < 4; ++mi)
    #pragma unroll
    for (int r = 0; r < 4; ++r) {
      int idx = l4 * 4 + r;
      int grow = q0 + mi * 16 + idx;
      #pragma unroll
      for (int ni = 0; ni < 4; ++ni)
        Opart[hoff + ((size_t)b * TT + grow) * DD + w * 64 + ni * 16 + l15] = o[mi][ni][r];
    }
  if (w == 0 && l15 == 0) {
    #pragma unroll
    for (int mi = 0; mi < 4; ++mi)
      #pragma unroll
      for (int r = 0; r < 4; ++r)
        Lp[(size_t)h * BB * TT + (size_t)b * TT + q0 + mi * 16 + l4 * 4 + r] =
            ls[mi][0][l4 * 4 + r] + ls[mi][1][l4 * 4 + r];
  }
}

// ---------------- K3: combine halves: Out = (O0 + O1) / (l0 + l1)
__global__ __launch_bounds__(256) void k_combine(
    const float* __restrict__ O0, const float* __restrict__ O1,
    const float* __restrict__ L0, const float* __restrict__ L1,
    float* __restrict__ Out)
{
  size_t i = (size_t)blockIdx.x * 256 + threadIdx.x;   // fv4 index
  size_t row = i >> 7;                                  // DD/4 = 128 fv4 per row
  float inv = 1.0f / (L0[row] + L1[row]);
  fv4 a = ((const fv4*)O0)[i];
  fv4 c = ((const fv4*)O1)[i];
  fv4 res;
  #pragma unroll
  for (int e = 0; e < 4; ++e) res[e] = (a[e] + c[e]) * inv;
  ((fv4*)Out)[i] = res;
}

extern "C" void kernel_launch(void* const* d_in, const int* in_sizes, int n_in,
                              void* d_out, int out_size, void* d_ws, size_t ws_size,
                              hipStream_t stream) {
  const float* ft_q = (const float*)d_in[0];
  const float* ft_k = (const float*)d_in[1];
  const float* ft_v = (const float*)d_in[2];
  const float* mask = (const float*)d_in[3];
  const float* Wq   = (const float*)d_in[4];
  const float* Wk   = (const float*)d_in[5];
  const float* Wv   = (const float*)d_in[6];
  float* Out = (float*)d_out;

  const size_t nBTD = (size_t)BB * TT * DD;   // 8,388,608
  short* Qb = (short*)d_ws;
  short* Kb = Qb + nBTD;
  short* Vb = Kb + nBTD;
  short* Vt = Vb + nBTD;
  float* O0 = (float*)(Vt + nBTD);
  float* O1 = O0 + nBTD;
  float* L0 = O1 + nBTD;
  float* L1 = L0 + (size_t)BB * TT;

  k_proj<<<dim3(128, 4, 3), 256, 0, stream>>>(ft_q, ft_k, ft_v, Wq, Wk, Wv, Qb, Kb, Vb);
  k_transpose<<<dim3(TT / 64, DD / 64, BB), 256, 0, stream>>>(Vb, Vt);
  k_attn<<<dim3(BB, TT / 64, 2), 512, 0, stream>>>(Qb, Kb, Vt, mask, O0, L0);
  k_combine<<<(unsigned)(nBTD / 4 / 256), 256, 0, stream>>>(O0, O1, L0, L1, Out);
}